// Round 1
// 108.644 us; speedup vs baseline: 1.0290x; 1.0290x over previous
//
#include <hip/hip_runtime.h>
#include <math.h>

#define N_NODES 3072
#define H_HEADS 8
#define IN_FEAT 64
#define OUT_FEAT 16
#define WORDS_PER_ROW 96               // 3072/32
#define MAXD 96                        // list cap; distinct-degree ~32, P(>96) ~ 1e-19
#define EDGES_PER_THREAD 4
#define WH_NPB 32                      // nodes per block in the Wh branch
#define WH_BLOCKS (N_NODES / WH_NPB)   // 96

// ---------------------------------------------------------------------------
// Fused: blocks [0, sb) scatter edges into the adjacency bitmask
// (single atomicOr per edge — bitmask dedups duplicates for free; 4 edges
// per thread via int4 loads); blocks [sb, ...) compute Wh (head-major, for
// aggregation reads) and e1t/e2t (head-minor, so main gathers all 8 heads
// in one 32B read).
// ---------------------------------------------------------------------------
__launch_bounds__(256)
__global__ void scatter_and_wh_kernel(const int* __restrict__ ei, int E,
                                      unsigned int* __restrict__ bits,
                                      const float* __restrict__ hfeat,
                                      const float* __restrict__ W,
                                      const float* __restrict__ a,
                                      float* __restrict__ Wh,
                                      float* __restrict__ e1t,
                                      float* __restrict__ e2t) {
    __shared__ __align__(16) float Wt[H_HEADS][OUT_FEAT][68];  // pad 64->68: no 2^k stride
    __shared__ __align__(16) float hs[WH_NPB][IN_FEAT];

    int tid = threadIdx.x;
    int sb = (E + 256 * EDGES_PER_THREAD - 1) / (256 * EDGES_PER_THREAD);
    if (blockIdx.x < sb) {
        int e0 = (blockIdx.x * 256 + tid) * EDGES_PER_THREAD;
        if (((E & 3) == 0) && (e0 + 3 < E)) {
            int4 r4 = *(const int4*)&ei[e0];
            int4 c4 = *(const int4*)&ei[E + e0];
            atomicOr(&bits[r4.x * WORDS_PER_ROW + (c4.x >> 5)], 1u << (c4.x & 31));
            atomicOr(&bits[r4.y * WORDS_PER_ROW + (c4.y >> 5)], 1u << (c4.y & 31));
            atomicOr(&bits[r4.z * WORDS_PER_ROW + (c4.z >> 5)], 1u << (c4.z & 31));
            atomicOr(&bits[r4.w * WORDS_PER_ROW + (c4.w >> 5)], 1u << (c4.w & 31));
        } else {
            for (int e = e0; e < E && e < e0 + EDGES_PER_THREAD; ++e) {
                int r = ei[e];       // row (softmax source)
                int c = ei[E + e];   // col (neighbor)
                atomicOr(&bits[r * WORDS_PER_ROW + (c >> 5)], 1u << (c & 31));
            }
        }
        return;
    }

    // ---- Wh branch ----
    int node_base = (blockIdx.x - sb) * WH_NPB;
    for (int idx = tid; idx < H_HEADS * IN_FEAT * OUT_FEAT; idx += 256) {
        int hh = idx >> 10, f = (idx >> 4) & 63, o = idx & 15;
        Wt[hh][o][f] = W[idx];           // transpose: coalesced global read
    }
    for (int idx = tid; idx < WH_NPB * IN_FEAT; idx += 256)
        hs[idx >> 6][idx & 63] = hfeat[node_base * IN_FEAT + idx];
    __syncthreads();

    int ng = tid >> 7;             // 0/1: which half of the nodes
    int hh = (tid >> 4) & 7;
    int o  = tid & 15;
    float a1v = a[hh * 2 * OUT_FEAT + o];
    float a2v = a[hh * 2 * OUT_FEAT + OUT_FEAT + o];

    float4 w[16];
#pragma unroll
    for (int q = 0; q < 16; ++q)
        w[q] = *(const float4*)&Wt[hh][o][4 * q];

    for (int n = ng; n < WH_NPB; n += 2) {
        float acc = 0.f;
#pragma unroll
        for (int q = 0; q < 16; ++q) {
            float4 hv = *(const float4*)&hs[n][4 * q];
            acc = fmaf(hv.x, w[q].x, acc);
            acc = fmaf(hv.y, w[q].y, acc);
            acc = fmaf(hv.z, w[q].z, acc);
            acc = fmaf(hv.w, w[q].w, acc);
        }
        int node = node_base + n;
        Wh[(hh * N_NODES + node) * OUT_FEAT + o] = acc;
        float p1 = acc * a1v, p2 = acc * a2v;
#pragma unroll
        for (int m = 1; m < 16; m <<= 1) {
            p1 += __shfl_xor(p1, m, 64);
            p2 += __shfl_xor(p2, m, 64);
        }
        if (o == 0) {
            e1t[node * H_HEADS + hh] = p1;   // head-minor
            e2t[node * H_HEADS + hh] = p2;
        }
    }
}

// ---------------------------------------------------------------------------
// One row per 256-thread block. All 4 waves decode the bitmask row in
// parallel (24 words each: popc + wave-local shuffle prefix scan + cross-wave
// offsets via LDS) into lds_j; then all threads gather S and the 8-head e2t
// vector per neighbor; then half-wave-per-head softmax (p = exp(v) directly;
// |v| <~ 55 so fp32 exp is safe) + float4-vectorized aggregation
// (half-wave = 8 neighbors x 4 feature-quads, dwordx4 Wh loads).
// ---------------------------------------------------------------------------
__launch_bounds__(256)
__global__ void gat_main_kernel(const unsigned int* __restrict__ bits,
                                const float* __restrict__ S,
                                const float* __restrict__ Wh,
                                const float* __restrict__ e1t,
                                const float* __restrict__ e2t,
                                const float* __restrict__ raw_gamma,
                                float* __restrict__ out) {
    __shared__ int lds_j[MAXD];
    __shared__ float lds_s[MAXD];
    __shared__ float lds_e2h[H_HEADS][MAXD];
    __shared__ float lds_p[H_HEADS][MAXD];
    __shared__ int lds_wtot[4];
    __shared__ int fb_j;
    int i = blockIdx.x;
    int tid = threadIdx.x;
    int wave = tid >> 6, lane = tid & 63;

    // ---- Phase A1: all 4 waves decode 24 words each of the bitmask row ----
    unsigned int w0 = 0u;
    if (lane < 24) w0 = bits[i * WORDS_PER_ROW + wave * 24 + lane];
    int c = __popc(w0);
    int s = c;
#pragma unroll
    for (int d = 1; d < 32; d <<= 1) {       // scan valid for lanes 0..31
        int v = __shfl_up(s, d, 64);
        if (lane >= d) s += v;
    }
    int wtot = __shfl(s, 23, 64);            // wave total (lanes 24+ are zero)
    if (lane == 0) lds_wtot[wave] = wtot;
    __syncthreads();
    int base = 0;
#pragma unroll
    for (int k = 0; k < 4; ++k)
        if (k < wave) base += lds_wtot[k];
    int cnt = lds_wtot[0] + lds_wtot[1] + lds_wtot[2] + lds_wtot[3];
    {
        int off = base + s - c;              // exclusive prefix within row
        unsigned int b = w0;
        int nbase = (wave * 24 + lane) << 5;
        while (b) {
            int bit = __ffs(b) - 1; b &= b - 1;
            if (off < MAXD) lds_j[off] = nbase + bit;
            ++off;
        }
    }
    __syncthreads();
    if (cnt > MAXD) cnt = MAXD;

    // ---- Phase A2: parallel gathers (S + all-heads e2t per neighbor) ----
    if (tid < cnt) {
        int j = lds_j[tid];
        lds_s[tid] = S[i * N_NODES + j];
        const float4* ep = (const float4*)&e2t[j * H_HEADS];
        float4 ea = ep[0], eb = ep[1];
        lds_e2h[0][tid] = ea.x; lds_e2h[1][tid] = ea.y;
        lds_e2h[2][tid] = ea.z; lds_e2h[3][tid] = ea.w;
        lds_e2h[4][tid] = eb.x; lds_e2h[5][tid] = eb.y;
        lds_e2h[6][tid] = eb.z; lds_e2h[7][tid] = eb.w;
    }
    __syncthreads();

    // ---- Degenerate row: softmax of all-masked row is one-hot at argmin S ----
    if (cnt == 0) {                      // block-uniform branch
        if (wave == 0) {
            float bm = 3.4e38f; int bj = 0;
            for (int j = lane; j < N_NODES; j += 64) {
                float sv = S[i * N_NODES + j];
                if (sv < bm) { bm = sv; bj = j; }
            }
            for (int m = 1; m < 64; m <<= 1) {
                float bm2 = __shfl_xor(bm, m, 64);
                int bj2 = __shfl_xor(bj, m, 64);
                if (bm2 < bm || (bm2 == bm && bj2 < bj)) { bm = bm2; bj = bj2; }
            }
            if (lane == 0) fb_j = bj;
        }
        __syncthreads();
        int jj = fb_j;
        if (tid < H_HEADS * OUT_FEAT) {
            int h2 = tid >> 4, o2 = tid & 15;
            float x = Wh[(h2 * N_NODES + jj) * OUT_FEAT + o2];
            out[i * (H_HEADS * OUT_FEAT) + h2 * OUT_FEAT + o2] =
                x > 0.f ? x : __expf(x) - 1.f;
        }
        return;
    }

    // ---- Phase B: half-wave per head ----
    int half = lane >> 5;
    int hl = lane & 31;
    int hh = wave * 2 + half;
    float g = log1pf(__expf(raw_gamma[hh]));       // softplus
    float e1v = e1t[i * H_HEADS + hh];
    float l = 0.f;
    for (int k = hl; k < cnt; k += 32) {
        float x = e1v + lds_e2h[hh][k];
        x = x > 0.f ? x : 0.2f * x;                // leaky_relu(., 0.2)
        float p = __expf(x * (1.f + g * lds_s[k]));
        lds_p[hh][k] = p;
        l += p;
    }
#pragma unroll
    for (int m = 1; m < 32; m <<= 1)               // stays within half-wave
        l += __shfl_xor(l, m, 64);

    // ---- aggregation: half-wave = 8 kgrps x 4 feature-quads (float4) ----
    int kgrp = hl >> 2;            // 0..7: which neighbor-slot
    int q = hl & 3;                // which feature quad (4 floats)
    float4 facc = make_float4(0.f, 0.f, 0.f, 0.f);
    for (int kk = kgrp; kk < cnt; kk += 8) {
        float p = lds_p[hh][kk];
        float4 wv = *(const float4*)&Wh[((hh * N_NODES + lds_j[kk]) << 4) + (q << 2)];
        facc.x = fmaf(p, wv.x, facc.x);
        facc.y = fmaf(p, wv.y, facc.y);
        facc.z = fmaf(p, wv.z, facc.z);
        facc.w = fmaf(p, wv.w, facc.w);
    }
#pragma unroll
    for (int m = 4; m < 32; m <<= 1) {             // reduce across the 8 kgrps
        facc.x += __shfl_xor(facc.x, m, 64);
        facc.y += __shfl_xor(facc.y, m, 64);
        facc.z += __shfl_xor(facc.z, m, 64);
        facc.w += __shfl_xor(facc.w, m, 64);
    }
    if (kgrp == 0) {
        float4 x;
        x.x = facc.x / l; x.y = facc.y / l;
        x.z = facc.z / l; x.w = facc.w / l;
        float4 o4;
        o4.x = x.x > 0.f ? x.x : __expf(x.x) - 1.f;   // elu
        o4.y = x.y > 0.f ? x.y : __expf(x.y) - 1.f;
        o4.z = x.z > 0.f ? x.z : __expf(x.z) - 1.f;
        o4.w = x.w > 0.f ? x.w : __expf(x.w) - 1.f;
        *(float4*)&out[i * (H_HEADS * OUT_FEAT) + hh * OUT_FEAT + (q << 2)] = o4;
    }
}

extern "C" void kernel_launch(void* const* d_in, const int* in_sizes, int n_in,
                              void* d_out, int out_size, void* d_ws, size_t ws_size,
                              hipStream_t stream) {
    const float* hfeat = (const float*)d_in[0];
    const int* ei      = (const int*)d_in[1];
    const float* S     = (const float*)d_in[2];
    const float* W     = (const float*)d_in[3];
    const float* a     = (const float*)d_in[4];
    const float* rg    = (const float*)d_in[5];
    float* out = (float*)d_out;

    char* ws = (char*)d_ws;
    // ws layout: bits 1,179,648 | Wh 1,572,864 | e1t 98,304 | e2t 98,304
    unsigned int* bits = (unsigned int*)ws;
    float* Wh = (float*)(ws + 1179648);
    float* e1t = (float*)(ws + 1179648 + 1572864);
    float* e2t = e1t + N_NODES * H_HEADS;

    hipMemsetAsync(bits, 0, (size_t)N_NODES * WORDS_PER_ROW * 4, stream);

    int E = in_sizes[1] / 2;
    int sb = (E + 256 * EDGES_PER_THREAD - 1) / (256 * EDGES_PER_THREAD);
    scatter_and_wh_kernel<<<sb + WH_BLOCKS, 256, 0, stream>>>(
        ei, E, bits, hfeat, W, a, Wh, e1t, e2t);

    gat_main_kernel<<<N_NODES, 256, 0, stream>>>(bits, S, Wh, e1t, e2t, rg, out);
}

// Round 2
// 107.291 us; speedup vs baseline: 1.0420x; 1.0126x over previous
//
#include <hip/hip_runtime.h>
#include <math.h>

#define N_NODES 3072
#define H_HEADS 8
#define IN_FEAT 64
#define OUT_FEAT 16
#define WORDS_PER_ROW 96               // 3072/32
#define MAXD 96                        // list cap; distinct-degree ~32, P(>96) ~ 1e-19
#define EDGES_PER_THREAD 4
#define WH_NPB 32                      // nodes per block in the Wh branch
#define WH_BLOCKS (N_NODES / WH_NPB)   // 96

// ---------------------------------------------------------------------------
// Fused: blocks [0, sb) scatter edges into the adjacency bitmask
// (single atomicOr per edge — bitmask dedups duplicates for free; 4 edges
// per thread via int4 loads); blocks [sb, ...) compute Wh (head-major, for
// aggregation reads) and e1t/e2t (head-minor, so main gathers all 8 heads
// in one 32B read).
// ---------------------------------------------------------------------------
__launch_bounds__(256)
__global__ void scatter_and_wh_kernel(const int* __restrict__ ei, int E,
                                      unsigned int* __restrict__ bits,
                                      const float* __restrict__ hfeat,
                                      const float* __restrict__ W,
                                      const float* __restrict__ a,
                                      float* __restrict__ Wh,
                                      float* __restrict__ e1t,
                                      float* __restrict__ e2t) {
    __shared__ __align__(16) float Wt[H_HEADS][OUT_FEAT][68];  // pad 64->68: no 2^k stride
    __shared__ __align__(16) float hs[WH_NPB][IN_FEAT];

    int tid = threadIdx.x;
    int sb = (E + 256 * EDGES_PER_THREAD - 1) / (256 * EDGES_PER_THREAD);
    if (blockIdx.x < sb) {
        int e0 = (blockIdx.x * 256 + tid) * EDGES_PER_THREAD;
        if (((E & 3) == 0) && (e0 + 3 < E)) {
            int4 r4 = *(const int4*)&ei[e0];
            int4 c4 = *(const int4*)&ei[E + e0];
            atomicOr(&bits[r4.x * WORDS_PER_ROW + (c4.x >> 5)], 1u << (c4.x & 31));
            atomicOr(&bits[r4.y * WORDS_PER_ROW + (c4.y >> 5)], 1u << (c4.y & 31));
            atomicOr(&bits[r4.z * WORDS_PER_ROW + (c4.z >> 5)], 1u << (c4.z & 31));
            atomicOr(&bits[r4.w * WORDS_PER_ROW + (c4.w >> 5)], 1u << (c4.w & 31));
        } else {
            for (int e = e0; e < E && e < e0 + EDGES_PER_THREAD; ++e) {
                int r = ei[e];       // row (softmax source)
                int c = ei[E + e];   // col (neighbor)
                atomicOr(&bits[r * WORDS_PER_ROW + (c >> 5)], 1u << (c & 31));
            }
        }
        return;
    }

    // ---- Wh branch ----
    int node_base = (blockIdx.x - sb) * WH_NPB;
    for (int idx = tid; idx < H_HEADS * IN_FEAT * OUT_FEAT; idx += 256) {
        int hh = idx >> 10, f = (idx >> 4) & 63, o = idx & 15;
        Wt[hh][o][f] = W[idx];           // transpose: coalesced global read
    }
    for (int idx = tid; idx < WH_NPB * IN_FEAT; idx += 256)
        hs[idx >> 6][idx & 63] = hfeat[node_base * IN_FEAT + idx];
    __syncthreads();

    int ng = tid >> 7;             // 0/1: which half of the nodes
    int hh = (tid >> 4) & 7;
    int o  = tid & 15;
    float a1v = a[hh * 2 * OUT_FEAT + o];
    float a2v = a[hh * 2 * OUT_FEAT + OUT_FEAT + o];

    float4 w[16];
#pragma unroll
    for (int q = 0; q < 16; ++q)
        w[q] = *(const float4*)&Wt[hh][o][4 * q];

    for (int n = ng; n < WH_NPB; n += 2) {
        float acc = 0.f;
#pragma unroll
        for (int q = 0; q < 16; ++q) {
            float4 hv = *(const float4*)&hs[n][4 * q];
            acc = fmaf(hv.x, w[q].x, acc);
            acc = fmaf(hv.y, w[q].y, acc);
            acc = fmaf(hv.z, w[q].z, acc);
            acc = fmaf(hv.w, w[q].w, acc);
        }
        int node = node_base + n;
        Wh[(hh * N_NODES + node) * OUT_FEAT + o] = acc;
        float p1 = acc * a1v, p2 = acc * a2v;
#pragma unroll
        for (int m = 1; m < 16; m <<= 1) {
            p1 += __shfl_xor(p1, m, 64);
            p2 += __shfl_xor(p2, m, 64);
        }
        if (o == 0) {
            e1t[node * H_HEADS + hh] = p1;   // head-minor
            e2t[node * H_HEADS + hh] = p2;
        }
    }
}

// ---------------------------------------------------------------------------
// One row per 128-thread block (2 waves — 3072 blocks x 2 = 6144 waves fits
// in ONE device occupancy round vs 12288 at 256 threads). Both waves decode
// 48 bitmask words each (popc + shuffle prefix scan) into lds_j; then all
// threads gather S and the 8-head e2t vector per neighbor; then 16 lanes
// per head: softmax (p = exp(v) directly; |v| <~ 55 so fp32 exp is safe)
// + float4-vectorized aggregation (4 neighbor-slots x 4 feature-quads —
// 8 in-flight dwordx4 Wh gathers per thread for latency hiding).
// ---------------------------------------------------------------------------
__launch_bounds__(128)
__global__ void gat_main_kernel(const unsigned int* __restrict__ bits,
                                const float* __restrict__ S,
                                const float* __restrict__ Wh,
                                const float* __restrict__ e1t,
                                const float* __restrict__ e2t,
                                const float* __restrict__ raw_gamma,
                                float* __restrict__ out) {
    __shared__ int lds_j[MAXD];
    __shared__ float lds_s[MAXD];
    __shared__ float lds_e2h[H_HEADS][MAXD];
    __shared__ float lds_p[H_HEADS][MAXD];
    __shared__ int lds_wtot[2];
    __shared__ int fb_j;
    int i = blockIdx.x;
    int tid = threadIdx.x;
    int wave = tid >> 6, lane = tid & 63;

    // ---- Phase A1: 2 waves decode 48 words each of the bitmask row ----
    unsigned int w0 = 0u;
    if (lane < 48) w0 = bits[i * WORDS_PER_ROW + wave * 48 + lane];
    int c = __popc(w0);
    int s = c;
#pragma unroll
    for (int d = 1; d < 64; d <<= 1) {
        int v = __shfl_up(s, d, 64);
        if (lane >= d) s += v;
    }
    int wtot = __shfl(s, 63, 64);            // lanes 48+ contribute 0
    if (lane == 0) lds_wtot[wave] = wtot;
    __syncthreads();
    int base = (wave == 1) ? lds_wtot[0] : 0;
    int cnt = lds_wtot[0] + lds_wtot[1];
    {
        int off = base + s - c;              // exclusive prefix within row
        unsigned int b = w0;
        int nbase = (wave * 48 + lane) << 5;
        while (b) {
            int bit = __ffs(b) - 1; b &= b - 1;
            if (off < MAXD) lds_j[off] = nbase + bit;
            ++off;
        }
    }
    __syncthreads();
    if (cnt > MAXD) cnt = MAXD;

    // ---- Phase A2: parallel gathers (S + all-heads e2t per neighbor) ----
    if (tid < cnt) {
        int j = lds_j[tid];
        lds_s[tid] = S[i * N_NODES + j];
        const float4* ep = (const float4*)&e2t[j * H_HEADS];
        float4 ea = ep[0], eb = ep[1];
        lds_e2h[0][tid] = ea.x; lds_e2h[1][tid] = ea.y;
        lds_e2h[2][tid] = ea.z; lds_e2h[3][tid] = ea.w;
        lds_e2h[4][tid] = eb.x; lds_e2h[5][tid] = eb.y;
        lds_e2h[6][tid] = eb.z; lds_e2h[7][tid] = eb.w;
    }
    __syncthreads();

    // ---- Degenerate row: softmax of all-masked row is one-hot at argmin S ----
    if (cnt == 0) {                      // block-uniform branch
        if (wave == 0) {
            float bm = 3.4e38f; int bj = 0;
            for (int j = lane; j < N_NODES; j += 64) {
                float sv = S[i * N_NODES + j];
                if (sv < bm) { bm = sv; bj = j; }
            }
            for (int m = 1; m < 64; m <<= 1) {
                float bm2 = __shfl_xor(bm, m, 64);
                int bj2 = __shfl_xor(bj, m, 64);
                if (bm2 < bm || (bm2 == bm && bj2 < bj)) { bm = bm2; bj = bj2; }
            }
            if (lane == 0) fb_j = bj;
        }
        __syncthreads();
        int jj = fb_j;
        // 128 threads == H_HEADS * OUT_FEAT exactly
        {
            int h2 = tid >> 4, o2 = tid & 15;
            float x = Wh[(h2 * N_NODES + jj) * OUT_FEAT + o2];
            out[i * (H_HEADS * OUT_FEAT) + h2 * OUT_FEAT + o2] =
                x > 0.f ? x : __expf(x) - 1.f;
        }
        return;
    }

    // ---- Phase B: 16 lanes per head (8 heads over 128 threads) ----
    int hh = tid >> 4;             // head
    int ll = tid & 15;             // lane within head-group (16-aligned in wave)
    float g = log1pf(__expf(raw_gamma[hh]));       // softplus
    float e1v = e1t[i * H_HEADS + hh];
    float l = 0.f;
    for (int k = ll; k < cnt; k += 16) {
        float x = e1v + lds_e2h[hh][k];
        x = x > 0.f ? x : 0.2f * x;                // leaky_relu(., 0.2)
        float p = __expf(x * (1.f + g * lds_s[k]));
        lds_p[hh][k] = p;
        l += p;
    }
#pragma unroll
    for (int m = 1; m < 16; m <<= 1)               // stays within 16-lane group
        l += __shfl_xor(l, m, 64);

    // ---- aggregation: 16 lanes = 4 kgrps x 4 feature-quads (float4) ----
    int kgrp = ll >> 2;            // 0..3: which neighbor-slot
    int q = ll & 3;                // which feature quad (4 floats)
    float4 facc = make_float4(0.f, 0.f, 0.f, 0.f);
    for (int kk = kgrp; kk < cnt; kk += 4) {
        float p = lds_p[hh][kk];
        float4 wv = *(const float4*)&Wh[((hh * N_NODES + lds_j[kk]) << 4) + (q << 2)];
        facc.x = fmaf(p, wv.x, facc.x);
        facc.y = fmaf(p, wv.y, facc.y);
        facc.z = fmaf(p, wv.z, facc.z);
        facc.w = fmaf(p, wv.w, facc.w);
    }
#pragma unroll
    for (int m = 4; m < 16; m <<= 1) {             // reduce across the 4 kgrps
        facc.x += __shfl_xor(facc.x, m, 64);
        facc.y += __shfl_xor(facc.y, m, 64);
        facc.z += __shfl_xor(facc.z, m, 64);
        facc.w += __shfl_xor(facc.w, m, 64);
    }
    if (kgrp == 0) {
        float4 x;
        x.x = facc.x / l; x.y = facc.y / l;
        x.z = facc.z / l; x.w = facc.w / l;
        float4 o4;
        o4.x = x.x > 0.f ? x.x : __expf(x.x) - 1.f;   // elu
        o4.y = x.y > 0.f ? x.y : __expf(x.y) - 1.f;
        o4.z = x.z > 0.f ? x.z : __expf(x.z) - 1.f;
        o4.w = x.w > 0.f ? x.w : __expf(x.w) - 1.f;
        *(float4*)&out[i * (H_HEADS * OUT_FEAT) + hh * OUT_FEAT + (q << 2)] = o4;
    }
}

extern "C" void kernel_launch(void* const* d_in, const int* in_sizes, int n_in,
                              void* d_out, int out_size, void* d_ws, size_t ws_size,
                              hipStream_t stream) {
    const float* hfeat = (const float*)d_in[0];
    const int* ei      = (const int*)d_in[1];
    const float* S     = (const float*)d_in[2];
    const float* W     = (const float*)d_in[3];
    const float* a     = (const float*)d_in[4];
    const float* rg    = (const float*)d_in[5];
    float* out = (float*)d_out;

    char* ws = (char*)d_ws;
    // ws layout: bits 1,179,648 | Wh 1,572,864 | e1t 98,304 | e2t 98,304
    unsigned int* bits = (unsigned int*)ws;
    float* Wh = (float*)(ws + 1179648);
    float* e1t = (float*)(ws + 1179648 + 1572864);
    float* e2t = e1t + N_NODES * H_HEADS;

    hipMemsetAsync(bits, 0, (size_t)N_NODES * WORDS_PER_ROW * 4, stream);

    int E = in_sizes[1] / 2;
    int sb = (E + 256 * EDGES_PER_THREAD - 1) / (256 * EDGES_PER_THREAD);
    scatter_and_wh_kernel<<<sb + WH_BLOCKS, 256, 0, stream>>>(
        ei, E, bits, hfeat, W, a, Wh, e1t, e2t);

    gat_main_kernel<<<N_NODES, 128, 0, stream>>>(bits, S, Wh, e1t, e2t, rg, out);
}